// Round 5
// baseline (8976.397 us; speedup 1.0000x reference)
//
#include <hip/hip_runtime.h>
#include <math.h>

#define D   512
#define BI  64
#define RR  36
#define BC  64
#define WW  40

// ---------------------------------------------------------------- row stats
__global__ __launch_bounds__(256) void row_stats_k(
    const float* __restrict__ X, const int* __restrict__ lens,
    int rpb, float2* __restrict__ out)
{
  int row = blockIdx.x;
  int b = row / rpb;
  int pos = row - b * rpb;
  bool valid = pos < lens[b];
  int tid = threadIdx.x;
  float s = 0.f, s2 = 0.f;
  if (valid) {
    float2 v = *(const float2*)(X + (size_t)row * D + tid * 2);
    s = v.x + v.y;
    s2 = v.x * v.x + v.y * v.y;
  }
  #pragma unroll
  for (int off = 32; off; off >>= 1) {
    s  += __shfl_down(s, off);
    s2 += __shfl_down(s2, off);
  }
  __shared__ float red[4][2];
  int wid = tid >> 6, lane = tid & 63;
  if (!lane) { red[wid][0] = s; red[wid][1] = s2; }
  __syncthreads();
  if (!tid) {
    s  = red[0][0] + red[1][0] + red[2][0] + red[3][0];
    s2 = red[0][1] + red[1][1] + red[2][1] + red[3][1];
    float mu  = s * (1.f / D);
    float var = s2 * (1.f / D) - mu * mu;
    out[row] = make_float2(mu, 1.f / sqrtf(fmaxf(var, 0.f) + 1e-5f));
  }
}

// ------------------------------------------------- pack Wo -> k-major float4
// Wo4[kb][n] (float4) = { Wo[n][4kb+0..3] },  kb in [0,128), n in [0,512)
__global__ __launch_bounds__(256) void pack_wo_k(
    const float4* __restrict__ Wo, float4* __restrict__ Wo4)
{
  int idx = blockIdx.x * 256 + threadIdx.x;   // 0..65535
  int kb = idx >> 9, n = idx & 511;
  Wo4[idx] = Wo[n * 128 + kb];
}

// ---------------------------------------------------------------- GEMM body
// C[M][ldc] = alpha * (A'[M][512] @ B[N][512]^T) + bias
// A' = A, optionally row-masked + LayerNorm'd (stats precomputed per row).
struct GemmP {
  const float* A; const float* Bm; float* C;
  int M, N, ldc; float alpha;
  const float* bias;
  const float2* stats; const float* g; const float* b;
  const int* lens; int rpb;
};

__device__ __forceinline__ void gemm_body(GemmP p, int bx, int by)
{
  __shared__ float As[16][132];
  __shared__ float Bs[16][132];
  int m0 = by * 128, n0 = bx * 128;
  int tid = threadIdx.x;
  int tm = tid & 15, tn = tid >> 4;
  float acc[8][8] = {{0.f}};
  for (int k0 = 0; k0 < D; k0 += 16) {
    #pragma unroll
    for (int l = 0; l < 2; ++l) {
      int fi  = tid + l * 256;        // 0..511
      int row = fi >> 2;              // 0..127
      int kq  = (fi & 3) << 2;        // 0,4,8,12
      {
        int gm = m0 + row;
        float4 x = *(const float4*)(p.A + (size_t)gm * D + k0 + kq);
        if (p.stats) {
          int bb = gm / p.rpb;
          bool val = (gm - bb * p.rpb) < p.lens[bb];
          float2 st = p.stats[gm];
          float4 gg  = *(const float4*)(p.g + k0 + kq);
          float4 bbv = *(const float4*)(p.b + k0 + kq);
          x.x = ((val ? x.x : 0.f) - st.x) * st.y * gg.x + bbv.x;
          x.y = ((val ? x.y : 0.f) - st.x) * st.y * gg.y + bbv.y;
          x.z = ((val ? x.z : 0.f) - st.x) * st.y * gg.z + bbv.z;
          x.w = ((val ? x.w : 0.f) - st.x) * st.y * gg.w + bbv.w;
        }
        As[kq + 0][row] = x.x; As[kq + 1][row] = x.y;
        As[kq + 2][row] = x.z; As[kq + 3][row] = x.w;
      }
      {
        float4 y = *(const float4*)(p.Bm + (size_t)(n0 + row) * D + k0 + kq);
        Bs[kq + 0][row] = y.x; Bs[kq + 1][row] = y.y;
        Bs[kq + 2][row] = y.z; Bs[kq + 3][row] = y.w;
      }
    }
    __syncthreads();
    #pragma unroll
    for (int kk = 0; kk < 16; ++kk) {
      float a[8], bb[8];
      *(float4*)(a)      = *(const float4*)&As[kk][tm * 8];
      *(float4*)(a + 4)  = *(const float4*)&As[kk][tm * 8 + 4];
      *(float4*)(bb)     = *(const float4*)&Bs[kk][tn * 8];
      *(float4*)(bb + 4) = *(const float4*)&Bs[kk][tn * 8 + 4];
      #pragma unroll
      for (int ii = 0; ii < 8; ++ii)
        #pragma unroll
        for (int jj = 0; jj < 8; ++jj)
          acc[ii][jj] = fmaf(a[ii], bb[jj], acc[ii][jj]);
    }
    __syncthreads();
  }
  #pragma unroll
  for (int ii = 0; ii < 8; ++ii) {
    int gm = m0 + tm * 8 + ii;
    #pragma unroll
    for (int jj = 0; jj < 8; jj += 4) {
      int gn = n0 + tn * 8 + jj;
      float4 o;
      o.x = acc[ii][jj+0] * p.alpha + (p.bias ? p.bias[gn+0] : 0.f);
      o.y = acc[ii][jj+1] * p.alpha + (p.bias ? p.bias[gn+1] : 0.f);
      o.z = acc[ii][jj+2] * p.alpha + (p.bias ? p.bias[gn+2] : 0.f);
      o.w = acc[ii][jj+3] * p.alpha + (p.bias ? p.bias[gn+3] : 0.f);
      *(float4*)(p.C + (size_t)gm * p.ldc + gn) = o;
    }
  }
}

// q/k/v projections: grid.z selects which projection.
__global__ __launch_bounds__(256) void qkv_gemm_k(
    const float* imgs, const float* caps,
    const float2* stats_img, const float2* stats_cap,
    const int* img_lens, const int* cap_lens,
    const float* Wq, const float* bq, const float* Wk, const float* bk,
    const float* Wv, const float* bv,
    const float* g1, const float* b1, const float* g2, const float* b2,
    const float* g3, const float* b3,
    float* qo, float* ko, float* vo)
{
  GemmP p;
  p.N = D; p.ldc = D; p.alpha = 1.f;
  int z = blockIdx.z;
  if (z == 0) {
    p.A = caps; p.stats = stats_cap; p.g = g1; p.b = b1;
    p.lens = cap_lens; p.rpb = WW;
    p.Bm = Wq; p.bias = bq; p.C = qo; p.M = BC * WW;
  } else if (z == 1) {
    p.A = imgs; p.stats = stats_img; p.g = g2; p.b = b2;
    p.lens = img_lens; p.rpb = RR;
    p.Bm = Wk; p.bias = bk; p.C = ko; p.M = BI * RR;
  } else {
    p.A = imgs; p.stats = stats_img; p.g = g3; p.b = b3;
    p.lens = img_lens; p.rpb = RR;
    p.Bm = Wv; p.bias = bv; p.C = vo; p.M = BI * RR;
  }
  if (blockIdx.y * 128 >= p.M) return;
  gemm_body(p, blockIdx.x, blockIdx.y);
}

// sims GEMM: S[cw][ir] = (1/sqrt(512)) * q[cw] . k[ir]
__global__ __launch_bounds__(256) void s_gemm_k(
    const float* q, const float* k, float* S)
{
  GemmP p;
  p.A = q; p.Bm = k; p.C = S;
  p.M = BC * WW; p.N = BI * RR; p.ldc = BI * RR;
  p.alpha = 0.04419417382415922f;   // 1/sqrt(512)
  p.bias = nullptr; p.stats = nullptr; p.g = nullptr; p.b = nullptr;
  p.lens = nullptr; p.rpb = 1;
  gemm_body(p, blockIdx.x, blockIdx.y);
}

// ------------------------------------------------------- masked row softmax
__global__ __launch_bounds__(256) void softmax36_k(
    float* __restrict__ S, const int* __restrict__ img_lens)
{
  int row = blockIdx.x * 256 + threadIdx.x;    // 0..163839 = (c*W+w)*64 + i
  int cw = row >> 6, i = row & 63;
  float* p = S + (size_t)cw * (BI * RR) + i * RR;
  int len = img_lens[i];
  float sv[RR];
  float m = -1e30f;
  #pragma unroll
  for (int r = 0; r < RR; ++r) {
    sv[r] = p[r];
    if (r < len && sv[r] > m) m = sv[r];
  }
  float sum = 0.f;
  #pragma unroll
  for (int r = 0; r < RR; ++r) {
    float e = (r < len) ? __expf(sv[r] - m) : 0.f;
    sv[r] = e; sum += e;
  }
  float inv = 1.f / sum;
  #pragma unroll
  for (int r = 0; r < RR; ++r) p[r] = sv[r] * inv;
}

// ------------------- fused: ctx = attn@v, LN, out = y@Wo^T+bo, cosine score
// Static LDS (161408 B <= 160 KiB arch max) — avoids the >64KB dynamic-LDS
// opt-in path (hipFuncSetAttribute), which is unreliable on ROCm.
__global__ __launch_bounds__(512) void fused_k(
    const float* __restrict__ q, const float* __restrict__ v,
    const float* __restrict__ attn, const float4* __restrict__ Wo4,
    const float* __restrict__ bo, const float* __restrict__ g4,
    const float* __restrict__ b4, const int* __restrict__ cap_lens,
    float* __restrict__ out)
{
  __shared__ float sm[(WW + RR) * D + WW * RR];   // 40352 f32 = 161408 B
  float* ybuf = sm;                     // 40*512 f32 (ctx -> y)
  float* vbuf = sm + WW * D;            // 36*512 f32 (v -> Wo slab)
  float* att  = sm + (WW + RR) * D;     // 1440 f32 (attn -> red/red2)
  const int i = blockIdx.x, c = blockIdx.y;
  const int tid = threadIdx.x;
  const int nb = tid & 127, wg = tid >> 7;
  const int lane = tid & 63;

  // ---- stage v_i and attn rows
  {
    const float4* vg = (const float4*)(v + (size_t)i * RR * D);
    float4* vb = (float4*)vbuf;
    for (int idx = tid; idx < RR * (D / 4); idx += 512) vb[idx] = vg[idx];
  }
  for (int idx = tid; idx < WW * RR; idx += 512) {
    int w = idx / RR;
    int r = idx - w * RR;
    att[idx] = attn[(size_t)(c * WW + w) * (BI * RR) + i * RR + r];
  }
  __syncthreads();

  // ---- ctx = attn @ v  -> ybuf   (thread: 10 w-rows x 4 consecutive d)
  {
    const int d4 = nb * 4;
    float ca[10][4];
    #pragma unroll
    for (int jw = 0; jw < 10; ++jw)
      ca[jw][0] = ca[jw][1] = ca[jw][2] = ca[jw][3] = 0.f;
    for (int r = 0; r < RR; ++r) {
      float4 v4 = *(const float4*)&vbuf[r * D + d4];
      #pragma unroll
      for (int jw = 0; jw < 10; ++jw) {
        float a = att[(wg * 10 + jw) * RR + r];
        ca[jw][0] = fmaf(a, v4.x, ca[jw][0]);
        ca[jw][1] = fmaf(a, v4.y, ca[jw][1]);
        ca[jw][2] = fmaf(a, v4.z, ca[jw][2]);
        ca[jw][3] = fmaf(a, v4.w, ca[jw][3]);
      }
    }
    #pragma unroll
    for (int jw = 0; jw < 10; ++jw)
      *(float4*)&ybuf[(wg * 10 + jw) * D + d4] =
          make_float4(ca[jw][0], ca[jw][1], ca[jw][2], ca[jw][3]);
  }
  __syncthreads();

  // ---- LN stats per ctx row (8 waves x 5 rows)
  float* red = att;   // [40][2] : mu, rsigma
  {
    int wid = tid >> 6;
    for (int w = wid; w < WW; w += 8) {
      float s = 0.f, s2 = 0.f;
      #pragma unroll
      for (int dd = 0; dd < D; dd += 64) {
        float x = ybuf[w * D + dd + lane];
        s += x; s2 += x * x;
      }
      #pragma unroll
      for (int off = 32; off; off >>= 1) {
        s  += __shfl_down(s, off);
        s2 += __shfl_down(s2, off);
      }
      if (!lane) {
        float mu  = s * (1.f / D);
        float var = s2 * (1.f / D) - mu * mu;
        red[w * 2]     = mu;
        red[w * 2 + 1] = 1.f / sqrtf(fmaxf(var, 0.f) + 1e-5f);
      }
    }
  }
  __syncthreads();

  // ---- apply LN in place (thread tid owns column d = tid)
  {
    float gg = g4[tid], bb = b4[tid];
    #pragma unroll
    for (int w = 0; w < WW; ++w) {
      float mu = red[w * 2], rs = red[w * 2 + 1];
      float x = ybuf[w * D + tid];
      ybuf[w * D + tid] = (x - mu) * rs * gg + bb;
    }
  }

  // ---- out = y @ Wo^T + bo, fused with num/den accumulation
  // thread owns columns n_j = nb + 128*j (j=0..3) for its 10 w-rows
  float oa[10][4];
  #pragma unroll
  for (int j = 0; j < 4; ++j) {
    float bj = bo[nb + 128 * j];
    #pragma unroll
    for (int jw = 0; jw < 10; ++jw) oa[jw][j] = bj;
  }
  float4* slab = (float4*)vbuf;   // [8][512] float4 Wo chunk
  for (int ch = 0; ch < 16; ++ch) {
    __syncthreads();              // previous chunk fully consumed
    #pragma unroll
    for (int l = 0; l < 8; ++l) {
      int fi = tid + l * 512;     // 0..4095 — linear copy
      slab[fi] = Wo4[ch * 4096 + fi];
    }
    __syncthreads();
    #pragma unroll
    for (int kbl = 0; kbl < 8; ++kbl) {
      float4 wo0 = slab[kbl * 512 + nb];
      float4 wo1 = slab[kbl * 512 + nb + 128];
      float4 wo2 = slab[kbl * 512 + nb + 256];
      float4 wo3 = slab[kbl * 512 + nb + 384];
      int kk = (ch * 8 + kbl) * 4;
      #pragma unroll
      for (int jw = 0; jw < 10; ++jw) {
        float4 y4 = *(const float4*)&ybuf[(wg * 10 + jw) * D + kk];
        oa[jw][0] += y4.x*wo0.x + y4.y*wo0.y + y4.z*wo0.z + y4.w*wo0.w;
        oa[jw][1] += y4.x*wo1.x + y4.y*wo1.y + y4.z*wo1.z + y4.w*wo1.w;
        oa[jw][2] += y4.x*wo2.x + y4.y*wo2.y + y4.z*wo2.z + y4.w*wo2.w;
        oa[jw][3] += y4.x*wo3.x + y4.y*wo3.y + y4.z*wo3.z + y4.w*wo3.w;
      }
    }
  }

  // ---- score: num = out.q, den = ||out||; reduce over n per w
  float* red2 = att + 80;   // [40][2 halves][2]
  const float* qbase = q + (size_t)c * WW * D;
  int h = (tid >> 6) & 1;
  #pragma unroll
  for (int jw = 0; jw < 10; ++jw) {
    int w = wg * 10 + jw;
    float np = 0.f, dp = 0.f;
    #pragma unroll
    for (int j = 0; j < 4; ++j) {
      float qv = qbase[(size_t)w * D + nb + 128 * j];
      np = fmaf(oa[jw][j], qv, np);
      dp = fmaf(oa[jw][j], oa[jw][j], dp);
    }
    #pragma unroll
    for (int off = 32; off; off >>= 1) {
      np += __shfl_down(np, off);
      dp += __shfl_down(dp, off);
    }
    if (!lane) {
      red2[(w * 2 + h) * 2]     = np;
      red2[(w * 2 + h) * 2 + 1] = dp;
    }
  }
  __syncthreads();
  if (tid < WW) {
    float num = red2[(tid * 2) * 2]     + red2[(tid * 2 + 1) * 2];
    float den = red2[(tid * 2) * 2 + 1] + red2[(tid * 2 + 1) * 2 + 1];
    float s = num / (sqrtf(den) + 1e-8f);
    out[((size_t)i * BC + c) * WW + tid] = (tid < cap_lens[c]) ? s : -1.0f;
  }
}

// ---------------------------------------------------------------------------
extern "C" void kernel_launch(void* const* d_in, const int* in_sizes, int n_in,
                              void* d_out, int out_size, void* d_ws, size_t ws_size,
                              hipStream_t stream)
{
  const float* imgs     = (const float*)d_in[0];
  const float* caps     = (const float*)d_in[1];
  const int*   img_lens = (const int*)d_in[2];
  const int*   cap_lens = (const int*)d_in[3];
  const float* Wq = (const float*)d_in[4];
  const float* bq = (const float*)d_in[5];
  const float* Wk = (const float*)d_in[6];
  const float* bk = (const float*)d_in[7];
  const float* Wv = (const float*)d_in[8];
  const float* bv = (const float*)d_in[9];
  const float* Wo = (const float*)d_in[10];
  const float* bo = (const float*)d_in[11];
  const float* g1 = (const float*)d_in[12];
  const float* b1 = (const float*)d_in[13];
  const float* g2 = (const float*)d_in[14];
  const float* b2 = (const float*)d_in[15];
  const float* g3 = (const float*)d_in[16];
  const float* b3 = (const float*)d_in[17];
  const float* g4 = (const float*)d_in[18];
  const float* b4 = (const float*)d_in[19];
  float* out = (float*)d_out;

  // Workspace layout (floats):
  //   stats_cap 2*2560 | stats_img 2*2304 | qb 2560*512 | kb 2304*512
  //   vb 2304*512 | Sb 2560*2304 | Wo4 512*512
  const size_t WS_FLOATS =
      (size_t)2 * (BC * WW) + 2 * (BI * RR) +
      (size_t)BC * WW * D + 2 * (size_t)BI * RR * D +
      (size_t)BC * WW * BI * RR + (size_t)D * D;
  if (ws_size < WS_FLOATS * sizeof(float)) return;  // guard: fault-free diag

  float*  ws        = (float*)d_ws;
  float2* stats_cap = (float2*)ws;                         // 2560
  float2* stats_img = stats_cap + BC * WW;                 // 2304
  float*  qb  = (float*)(stats_img + BI * RR);             // 2560*512
  float*  kb  = qb + (size_t)BC * WW * D;                  // 2304*512
  float*  vb  = kb + (size_t)BI * RR * D;                  // 2304*512
  float*  Sb  = vb + (size_t)BI * RR * D;                  // 2560*2304
  float*  Wo4 = Sb + (size_t)BC * WW * BI * RR;            // 512*512

  row_stats_k<<<BC * WW, 256, 0, stream>>>(caps, cap_lens, WW, stats_cap);
  row_stats_k<<<BI * RR, 256, 0, stream>>>(imgs, img_lens, RR, stats_img);
  pack_wo_k<<<(D * (D / 4)) / 256, 256, 0, stream>>>((const float4*)Wo, (float4*)Wo4);

  qkv_gemm_k<<<dim3(4, 20, 3), 256, 0, stream>>>(
      imgs, caps, stats_img, stats_cap, img_lens, cap_lens,
      Wq, bq, Wk, bk, Wv, bv, g1, b1, g2, b2, g3, b3, qb, kb, vb);

  s_gemm_k<<<dim3(18, 20), 256, 0, stream>>>(qb, kb, Sb);

  softmax36_k<<<640, 256, 0, stream>>>(Sb, img_lens);

  fused_k<<<dim3(BI, BC), 512, 0, stream>>>(
      qb, vb, Sb, (const float4*)Wo4, bo, g4, b4, cap_lens, out);
}

// Round 6
// 8963.734 us; speedup vs baseline: 1.0014x; 1.0014x over previous
//
#include <hip/hip_runtime.h>
#include <math.h>

#define D   512
#define BI  64
#define RR  36
#define BC  64
#define WW  40

// ---------------------------------------------------------------- row stats
__global__ __launch_bounds__(256) void row_stats_k(
    const float* __restrict__ X, const int* __restrict__ lens,
    int rpb, float2* __restrict__ out)
{
  int row = blockIdx.x;
  int b = row / rpb;
  int pos = row - b * rpb;
  bool valid = pos < lens[b];
  int tid = threadIdx.x;
  float s = 0.f, s2 = 0.f;
  if (valid) {
    float2 v = *(const float2*)(X + (size_t)row * D + tid * 2);
    s = v.x + v.y;
    s2 = v.x * v.x + v.y * v.y;
  }
  #pragma unroll
  for (int off = 32; off; off >>= 1) {
    s  += __shfl_down(s, off);
    s2 += __shfl_down(s2, off);
  }
  __shared__ float red[4][2];
  int wid = tid >> 6, lane = tid & 63;
  if (!lane) { red[wid][0] = s; red[wid][1] = s2; }
  __syncthreads();
  if (!tid) {
    s  = red[0][0] + red[1][0] + red[2][0] + red[3][0];
    s2 = red[0][1] + red[1][1] + red[2][1] + red[3][1];
    float mu  = s * (1.f / D);
    float var = s2 * (1.f / D) - mu * mu;
    out[row] = make_float2(mu, 1.f / sqrtf(fmaxf(var, 0.f) + 1e-5f));
  }
}

// ------------------------------------------------- pack Wo -> k-major float4
// Wo4[kb][n] (float4) = { Wo[n][4kb+0..3] },  kb in [0,128), n in [0,512)
__global__ __launch_bounds__(256) void pack_wo_k(
    const float4* __restrict__ Wo, float4* __restrict__ Wo4)
{
  int idx = blockIdx.x * 256 + threadIdx.x;   // 0..65535
  int kb = idx >> 9, n = idx & 511;
  Wo4[idx] = Wo[n * 128 + kb];
}

// ---------------------------------------------------------------- GEMM body
// C[M][ldc] = alpha * (A'[M][512] @ B[N][512]^T) + bias
// A' = A, optionally row-masked + LayerNorm'd (stats precomputed per row).
struct GemmP {
  const float* A; const float* Bm; float* C;
  int M, N, ldc; float alpha;
  const float* bias;
  const float2* stats; const float* g; const float* b;
  const int* lens; int rpb;
};

__device__ __forceinline__ void gemm_body(GemmP p, int bx, int by)
{
  __shared__ float As[16][132];
  __shared__ float Bs[16][132];
  int m0 = by * 128, n0 = bx * 128;
  int tid = threadIdx.x;
  int tm = tid & 15, tn = tid >> 4;
  float acc[8][8] = {{0.f}};
  for (int k0 = 0; k0 < D; k0 += 16) {
    #pragma unroll
    for (int l = 0; l < 2; ++l) {
      int fi  = tid + l * 256;        // 0..511
      int row = fi >> 2;              // 0..127
      int kq  = (fi & 3) << 2;        // 0,4,8,12
      {
        int gm = m0 + row;
        float4 x = *(const float4*)(p.A + (size_t)gm * D + k0 + kq);
        if (p.stats) {
          int bb = gm / p.rpb;
          bool val = (gm - bb * p.rpb) < p.lens[bb];
          float2 st = p.stats[gm];
          float4 gg  = *(const float4*)(p.g + k0 + kq);
          float4 bbv = *(const float4*)(p.b + k0 + kq);
          x.x = ((val ? x.x : 0.f) - st.x) * st.y * gg.x + bbv.x;
          x.y = ((val ? x.y : 0.f) - st.x) * st.y * gg.y + bbv.y;
          x.z = ((val ? x.z : 0.f) - st.x) * st.y * gg.z + bbv.z;
          x.w = ((val ? x.w : 0.f) - st.x) * st.y * gg.w + bbv.w;
        }
        As[kq + 0][row] = x.x; As[kq + 1][row] = x.y;
        As[kq + 2][row] = x.z; As[kq + 3][row] = x.w;
      }
      {
        float4 y = *(const float4*)(p.Bm + (size_t)(n0 + row) * D + k0 + kq);
        Bs[kq + 0][row] = y.x; Bs[kq + 1][row] = y.y;
        Bs[kq + 2][row] = y.z; Bs[kq + 3][row] = y.w;
      }
    }
    __syncthreads();
    #pragma unroll
    for (int kk = 0; kk < 16; ++kk) {
      float a[8], bb[8];
      *(float4*)(a)      = *(const float4*)&As[kk][tm * 8];
      *(float4*)(a + 4)  = *(const float4*)&As[kk][tm * 8 + 4];
      *(float4*)(bb)     = *(const float4*)&Bs[kk][tn * 8];
      *(float4*)(bb + 4) = *(const float4*)&Bs[kk][tn * 8 + 4];
      #pragma unroll
      for (int ii = 0; ii < 8; ++ii)
        #pragma unroll
        for (int jj = 0; jj < 8; ++jj)
          acc[ii][jj] = fmaf(a[ii], bb[jj], acc[ii][jj]);
    }
    __syncthreads();
  }
  #pragma unroll
  for (int ii = 0; ii < 8; ++ii) {
    int gm = m0 + tm * 8 + ii;
    #pragma unroll
    for (int jj = 0; jj < 8; jj += 4) {
      int gn = n0 + tn * 8 + jj;
      float4 o;
      o.x = acc[ii][jj+0] * p.alpha + (p.bias ? p.bias[gn+0] : 0.f);
      o.y = acc[ii][jj+1] * p.alpha + (p.bias ? p.bias[gn+1] : 0.f);
      o.z = acc[ii][jj+2] * p.alpha + (p.bias ? p.bias[gn+2] : 0.f);
      o.w = acc[ii][jj+3] * p.alpha + (p.bias ? p.bias[gn+3] : 0.f);
      *(float4*)(p.C + (size_t)gm * p.ldc + gn) = o;
    }
  }
}

// q/k/v projections: grid.z selects which projection.
__global__ __launch_bounds__(256) void qkv_gemm_k(
    const float* imgs, const float* caps,
    const float2* stats_img, const float2* stats_cap,
    const int* img_lens, const int* cap_lens,
    const float* Wq, const float* bq, const float* Wk, const float* bk,
    const float* Wv, const float* bv,
    const float* g1, const float* b1, const float* g2, const float* b2,
    const float* g3, const float* b3,
    float* qo, float* ko, float* vo)
{
  GemmP p;
  p.N = D; p.ldc = D; p.alpha = 1.f;
  int z = blockIdx.z;
  if (z == 0) {
    p.A = caps; p.stats = stats_cap; p.g = g1; p.b = b1;
    p.lens = cap_lens; p.rpb = WW;
    p.Bm = Wq; p.bias = bq; p.C = qo; p.M = BC * WW;
  } else if (z == 1) {
    p.A = imgs; p.stats = stats_img; p.g = g2; p.b = b2;
    p.lens = img_lens; p.rpb = RR;
    p.Bm = Wk; p.bias = bk; p.C = ko; p.M = BI * RR;
  } else {
    p.A = imgs; p.stats = stats_img; p.g = g3; p.b = b3;
    p.lens = img_lens; p.rpb = RR;
    p.Bm = Wv; p.bias = bv; p.C = vo; p.M = BI * RR;
  }
  if (blockIdx.y * 128 >= p.M) return;
  gemm_body(p, blockIdx.x, blockIdx.y);
}

// sims GEMM: S[cw][ir] = (1/sqrt(512)) * q[cw] . k[ir]
__global__ __launch_bounds__(256) void s_gemm_k(
    const float* q, const float* k, float* S)
{
  GemmP p;
  p.A = q; p.Bm = k; p.C = S;
  p.M = BC * WW; p.N = BI * RR; p.ldc = BI * RR;
  p.alpha = 0.04419417382415922f;   // 1/sqrt(512)
  p.bias = nullptr; p.stats = nullptr; p.g = nullptr; p.b = nullptr;
  p.lens = nullptr; p.rpb = 1;
  gemm_body(p, blockIdx.x, blockIdx.y);
}

// ------------------------------------------------------- masked row softmax
__global__ __launch_bounds__(256) void softmax36_k(
    float* __restrict__ S, const int* __restrict__ img_lens)
{
  int row = blockIdx.x * 256 + threadIdx.x;    // 0..163839 = (c*W+w)*64 + i
  int cw = row >> 6, i = row & 63;
  float* p = S + (size_t)cw * (BI * RR) + i * RR;
  int len = img_lens[i];
  float sv[RR];
  float m = -1e30f;
  #pragma unroll
  for (int r = 0; r < RR; ++r) {
    sv[r] = p[r];
    if (r < len && sv[r] > m) m = sv[r];
  }
  float sum = 0.f;
  #pragma unroll
  for (int r = 0; r < RR; ++r) {
    float e = (r < len) ? __expf(sv[r] - m) : 0.f;
    sv[r] = e; sum += e;
  }
  float inv = 1.f / sum;
  #pragma unroll
  for (int r = 0; r < RR; ++r) p[r] = sv[r] * inv;
}

// ------------------- fused: ctx = attn@v, LN, out = y@Wo^T+bo, cosine score
// __launch_bounds__(512, 2): block is 1/CU anyway (158 KiB LDS -> 2 waves/
// SIMD), so the VGPR cap can be 256 instead of the default 128. R5 counters
// showed 19.5 GB scratch WRITE_SIZE (vs 0.65 MB logical) = register spill of
// the oa/ca accumulator arrays at the 128-reg cap; this lifts the cap at
// ZERO occupancy cost.
__global__ __launch_bounds__(512, 2) void fused_k(
    const float* __restrict__ q, const float* __restrict__ v,
    const float* __restrict__ attn, const float4* __restrict__ Wo4,
    const float* __restrict__ bo, const float* __restrict__ g4,
    const float* __restrict__ b4, const int* __restrict__ cap_lens,
    float* __restrict__ out)
{
  __shared__ float sm[(WW + RR) * D + WW * RR];   // 40352 f32 = 161408 B
  float* ybuf = sm;                     // 40*512 f32 (ctx -> y)
  float* vbuf = sm + WW * D;            // 36*512 f32 (v -> Wo slab)
  float* att  = sm + (WW + RR) * D;     // 1440 f32 (attn -> red/red2)
  const int i = blockIdx.x, c = blockIdx.y;
  const int tid = threadIdx.x;
  const int nb = tid & 127, wg = tid >> 7;
  const int lane = tid & 63;

  // ---- stage v_i and attn rows
  {
    const float4* vg = (const float4*)(v + (size_t)i * RR * D);
    float4* vb = (float4*)vbuf;
    for (int idx = tid; idx < RR * (D / 4); idx += 512) vb[idx] = vg[idx];
  }
  for (int idx = tid; idx < WW * RR; idx += 512) {
    int w = idx / RR;
    int r = idx - w * RR;
    att[idx] = attn[(size_t)(c * WW + w) * (BI * RR) + i * RR + r];
  }
  __syncthreads();

  // ---- ctx = attn @ v  -> ybuf   (thread: 10 w-rows x 4 consecutive d)
  {
    const int d4 = nb * 4;
    float ca[10][4];
    #pragma unroll
    for (int jw = 0; jw < 10; ++jw)
      ca[jw][0] = ca[jw][1] = ca[jw][2] = ca[jw][3] = 0.f;
    for (int r = 0; r < RR; ++r) {
      float4 v4 = *(const float4*)&vbuf[r * D + d4];
      #pragma unroll
      for (int jw = 0; jw < 10; ++jw) {
        float a = att[(wg * 10 + jw) * RR + r];
        ca[jw][0] = fmaf(a, v4.x, ca[jw][0]);
        ca[jw][1] = fmaf(a, v4.y, ca[jw][1]);
        ca[jw][2] = fmaf(a, v4.z, ca[jw][2]);
        ca[jw][3] = fmaf(a, v4.w, ca[jw][3]);
      }
    }
    #pragma unroll
    for (int jw = 0; jw < 10; ++jw)
      *(float4*)&ybuf[(wg * 10 + jw) * D + d4] =
          make_float4(ca[jw][0], ca[jw][1], ca[jw][2], ca[jw][3]);
  }
  __syncthreads();

  // ---- LN stats per ctx row (8 waves x 5 rows)
  float* red = att;   // [40][2] : mu, rsigma
  {
    int wid = tid >> 6;
    for (int w = wid; w < WW; w += 8) {
      float s = 0.f, s2 = 0.f;
      #pragma unroll
      for (int dd = 0; dd < D; dd += 64) {
        float x = ybuf[w * D + dd + lane];
        s += x; s2 += x * x;
      }
      #pragma unroll
      for (int off = 32; off; off >>= 1) {
        s  += __shfl_down(s, off);
        s2 += __shfl_down(s2, off);
      }
      if (!lane) {
        float mu  = s * (1.f / D);
        float var = s2 * (1.f / D) - mu * mu;
        red[w * 2]     = mu;
        red[w * 2 + 1] = 1.f / sqrtf(fmaxf(var, 0.f) + 1e-5f);
      }
    }
  }
  __syncthreads();

  // ---- apply LN in place (thread tid owns column d = tid)
  {
    float gg = g4[tid], bb = b4[tid];
    #pragma unroll
    for (int w = 0; w < WW; ++w) {
      float mu = red[w * 2], rs = red[w * 2 + 1];
      float x = ybuf[w * D + tid];
      ybuf[w * D + tid] = (x - mu) * rs * gg + bb;
    }
  }

  // ---- out = y @ Wo^T + bo, fused with num/den accumulation
  // thread owns columns n_j = nb + 128*j (j=0..3) for its 10 w-rows
  float oa[10][4];
  #pragma unroll
  for (int j = 0; j < 4; ++j) {
    float bj = bo[nb + 128 * j];
    #pragma unroll
    for (int jw = 0; jw < 10; ++jw) oa[jw][j] = bj;
  }
  float4* slab = (float4*)vbuf;   // [8][512] float4 Wo chunk
  for (int ch = 0; ch < 16; ++ch) {
    __syncthreads();              // previous chunk fully consumed
    #pragma unroll
    for (int l = 0; l < 8; ++l) {
      int fi = tid + l * 512;     // 0..4095 — linear copy
      slab[fi] = Wo4[ch * 4096 + fi];
    }
    __syncthreads();
    #pragma unroll
    for (int kbl = 0; kbl < 8; ++kbl) {
      float4 wo0 = slab[kbl * 512 + nb];
      float4 wo1 = slab[kbl * 512 + nb + 128];
      float4 wo2 = slab[kbl * 512 + nb + 256];
      float4 wo3 = slab[kbl * 512 + nb + 384];
      int kk = (ch * 8 + kbl) * 4;
      #pragma unroll
      for (int jw = 0; jw < 10; ++jw) {
        float4 y4 = *(const float4*)&ybuf[(wg * 10 + jw) * D + kk];
        oa[jw][0] += y4.x*wo0.x + y4.y*wo0.y + y4.z*wo0.z + y4.w*wo0.w;
        oa[jw][1] += y4.x*wo1.x + y4.y*wo1.y + y4.z*wo1.z + y4.w*wo1.w;
        oa[jw][2] += y4.x*wo2.x + y4.y*wo2.y + y4.z*wo2.z + y4.w*wo2.w;
        oa[jw][3] += y4.x*wo3.x + y4.y*wo3.y + y4.z*wo3.z + y4.w*wo3.w;
      }
    }
  }

  // ---- score: num = out.q, den = ||out||; reduce over n per w
  float* red2 = att + 80;   // [40][2 halves][2]
  const float* qbase = q + (size_t)c * WW * D;
  int h = (tid >> 6) & 1;
  #pragma unroll
  for (int jw = 0; jw < 10; ++jw) {
    int w = wg * 10 + jw;
    float np = 0.f, dp = 0.f;
    #pragma unroll
    for (int j = 0; j < 4; ++j) {
      float qv = qbase[(size_t)w * D + nb + 128 * j];
      np = fmaf(oa[jw][j], qv, np);
      dp = fmaf(oa[jw][j], oa[jw][j], dp);
    }
    #pragma unroll
    for (int off = 32; off; off >>= 1) {
      np += __shfl_down(np, off);
      dp += __shfl_down(dp, off);
    }
    if (!lane) {
      red2[(w * 2 + h) * 2]     = np;
      red2[(w * 2 + h) * 2 + 1] = dp;
    }
  }
  __syncthreads();
  if (tid < WW) {
    float num = red2[(tid * 2) * 2]     + red2[(tid * 2 + 1) * 2];
    float den = red2[(tid * 2) * 2 + 1] + red2[(tid * 2 + 1) * 2 + 1];
    float s = num / (sqrtf(den) + 1e-8f);
    out[((size_t)i * BC + c) * WW + tid] = (tid < cap_lens[c]) ? s : -1.0f;
  }
}

// ---------------------------------------------------------------------------
extern "C" void kernel_launch(void* const* d_in, const int* in_sizes, int n_in,
                              void* d_out, int out_size, void* d_ws, size_t ws_size,
                              hipStream_t stream)
{
  const float* imgs     = (const float*)d_in[0];
  const float* caps     = (const float*)d_in[1];
  const int*   img_lens = (const int*)d_in[2];
  const int*   cap_lens = (const int*)d_in[3];
  const float* Wq = (const float*)d_in[4];
  const float* bq = (const float*)d_in[5];
  const float* Wk = (const float*)d_in[6];
  const float* bk = (const float*)d_in[7];
  const float* Wv = (const float*)d_in[8];
  const float* bv = (const float*)d_in[9];
  const float* Wo = (const float*)d_in[10];
  const float* bo = (const float*)d_in[11];
  const float* g1 = (const float*)d_in[12];
  const float* b1 = (const float*)d_in[13];
  const float* g2 = (const float*)d_in[14];
  const float* b2 = (const float*)d_in[15];
  const float* g3 = (const float*)d_in[16];
  const float* b3 = (const float*)d_in[17];
  const float* g4 = (const float*)d_in[18];
  const float* b4 = (const float*)d_in[19];
  float* out = (float*)d_out;

  // Workspace layout (floats):
  //   stats_cap 2*2560 | stats_img 2*2304 | qb 2560*512 | kb 2304*512
  //   vb 2304*512 | Sb 2560*2304 | Wo4 512*512
  const size_t WS_FLOATS =
      (size_t)2 * (BC * WW) + 2 * (BI * RR) +
      (size_t)BC * WW * D + 2 * (size_t)BI * RR * D +
      (size_t)BC * WW * BI * RR + (size_t)D * D;
  if (ws_size < WS_FLOATS * sizeof(float)) return;  // guard: fault-free diag

  float*  ws        = (float*)d_ws;
  float2* stats_cap = (float2*)ws;                         // 2560
  float2* stats_img = stats_cap + BC * WW;                 // 2304
  float*  qb  = (float*)(stats_img + BI * RR);             // 2560*512
  float*  kb  = qb + (size_t)BC * WW * D;                  // 2304*512
  float*  vb  = kb + (size_t)BI * RR * D;                  // 2304*512
  float*  Sb  = vb + (size_t)BI * RR * D;                  // 2560*2304
  float*  Wo4 = Sb + (size_t)BC * WW * BI * RR;            // 512*512

  row_stats_k<<<BC * WW, 256, 0, stream>>>(caps, cap_lens, WW, stats_cap);
  row_stats_k<<<BI * RR, 256, 0, stream>>>(imgs, img_lens, RR, stats_img);
  pack_wo_k<<<(D * (D / 4)) / 256, 256, 0, stream>>>((const float4*)Wo, (float4*)Wo4);

  qkv_gemm_k<<<dim3(4, 20, 3), 256, 0, stream>>>(
      imgs, caps, stats_img, stats_cap, img_lens, cap_lens,
      Wq, bq, Wk, bk, Wv, bv, g1, b1, g2, b2, g3, b3, qb, kb, vb);

  s_gemm_k<<<dim3(18, 20), 256, 0, stream>>>(qb, kb, Sb);

  softmax36_k<<<640, 256, 0, stream>>>(Sb, img_lens);

  fused_k<<<dim3(BI, BC), 512, 0, stream>>>(
      qb, vb, Sb, (const float4*)Wo4, bo, g4, b4, cap_lens, out);
}